// Round 8
// baseline (158.783 us; speedup 1.0000x reference)
//
#include <hip/hip_runtime.h>

#define BB 2
#define LL 512
#define DD 64
#define HH 8
#define GG 64
#define KK 4
#define NEGV -1e9f
#define NSLOT 36

typedef unsigned short ushort_t;
typedef __attribute__((ext_vector_type(8))) short bf16x8;
typedef __attribute__((ext_vector_type(4))) float f32x4;
#define MFMA(a, b, c) __builtin_amdgcn_mfma_f32_16x16x32_bf16(a, b, c, 0, 0, 0)

__device__ __forceinline__ ushort_t f2b(float f) {
    unsigned int u = __float_as_uint(f);
    return (ushort_t)((u + 0x7FFFu + ((u >> 16) & 1u)) >> 16);
}
__device__ __forceinline__ float b2f(ushort_t s) {
    return __uint_as_float(((unsigned int)s) << 16);
}

// stage a 64x64 bf16 tile (row-major, rowstride elems) into LDS with granule-XOR swizzle
__device__ __forceinline__ void stage64(ushort_t* dst, const ushort_t* src,
                                        int rowstride, int tid) {
#pragma unroll
    for (int g = tid; g < 512; g += 256) {
        int row = g >> 3, colg = g & 7;
        uint4 v = *reinterpret_cast<const uint4*>(&src[row * rowstride + (colg << 3)]);
        *reinterpret_cast<uint4*>(&dst[(row << 6) + ((colg ^ (row & 7)) << 3)]) = v;
    }
}
// read an 8-elem fragment (col multiple of 8) from swizzled LDS tile
__device__ __forceinline__ bf16x8 frag(const ushort_t* s, int row, int col) {
    return *reinterpret_cast<const bf16x8*>(&s[(row << 6) + ((((col >> 3) ^ (row & 7))) << 3)]);
}
__device__ __forceinline__ bf16x8 maskfrag(bf16x8 v, int cnt, bool keep_prefix) {
    bf16x8 r;
#pragma unroll
    for (int u = 0; u < 8; ++u) {
        bool keep = keep_prefix ? (u < cnt) : (u >= cnt);
        r[u] = keep ? v[u] : (short)0;
    }
    return r;
}
__device__ __forceinline__ int iclamp(int v, int lo, int hi) {
    return v < lo ? lo : (v > hi ? hi : v);
}

// ---------------- K0 (once): T -> bf16 MFMA operand tiles ----------------
__global__ __launch_bounds__(256) void k_prepT(const float* __restrict__ T,
                                               ushort_t* __restrict__ TB1,
                                               ushort_t* __restrict__ TB2) {
    int k = blockIdx.x >> 3, c = blockIdx.x & 7;   // 32 blocks
    int tid = threadIdx.x;
    for (int g = tid; g < 512; g += 256) {
        int a = g >> 3, b0 = (g & 7) * 8;
        ushort_t o1[8], o2[8];
#pragma unroll
        for (int u = 0; u < 8; ++u) {
            o1[u] = f2b(T[(((k * 64 + a) * 64) + b0 + u) * 8 + c]);
            o2[u] = f2b(T[(((k * 64 + b0 + u) * 64) + a) * 8 + c]);
        }
        size_t base = ((size_t)(k * 8 + c) * 64 + a) * 64 + b0;
        *reinterpret_cast<uint4*>(&TB1[base]) = *reinterpret_cast<uint4*>(o1);
        *reinterpret_cast<uint4*>(&TB2[base]) = *reinterpret_cast<uint4*>(o2);
    }
}

// ---------------- K1: Q_z = softmax(q_z) over d=64; fp32 + bf16 outputs ----------------
__global__ __launch_bounds__(256) void k_softmax_qz(const float* __restrict__ src,
                                                    float* __restrict__ Qz,
                                                    ushort_t* __restrict__ QzB) {
    int row = blockIdx.x * 4 + (threadIdx.x >> 6);
    int lane = threadIdx.x & 63;
    float v = src[row * DD + lane];
    float m = v;
#pragma unroll
    for (int o = 32; o > 0; o >>= 1) m = fmaxf(m, __shfl_xor(m, o, 64));
    float e = __expf(v - m);
    float s = e;
#pragma unroll
    for (int o = 32; o > 0; o >>= 1) s += __shfl_xor(s, o, 64);
    float r = e / s;
    Qz[row * DD + lane] = r;
    QzB[row * DD + lane] = f2b(r);
}

// ---------------- K2: M1/M2 via MFMA ----------------
__global__ __launch_bounds__(256) void k_compute_M(const ushort_t* __restrict__ QzB,
        const ushort_t* __restrict__ TB1, const ushort_t* __restrict__ TB2,
        ushort_t* __restrict__ M1Nb, ushort_t* __restrict__ M2Nb) {
    int jt = blockIdx.x, c = blockIdx.y;
    int z = blockIdx.z >> 2, k = blockIdx.z & 3;
    __shared__ ushort_t sQ[4096], sB1[4096], sB2[4096];
    int tid = threadIdx.x;
    stage64(sQ, QzB + (size_t)(z * LL + jt * 64) * DD, DD, tid);
    size_t tb = (size_t)(k * 8 + c) * 4096;
    stage64(sB1, TB1 + tb, 64, tid);
    stage64(sB2, TB2 + tb, 64, tid);
    __syncthreads();
    int w = tid >> 6, lm = tid & 15, lg = (tid & 63) >> 4;
    f32x4 a1[4], a2[4];
#pragma unroll
    for (int nf = 0; nf < 4; ++nf) { a1[nf] = {0.f,0.f,0.f,0.f}; a2[nf] = {0.f,0.f,0.f,0.f}; }
#pragma unroll
    for (int ks = 0; ks < 2; ++ks) {
        int kc = ks * 32 + lg * 8;
        bf16x8 af = frag(sQ, w * 16 + lm, kc);
#pragma unroll
        for (int nf = 0; nf < 4; ++nf) {
            a1[nf] = MFMA(af, frag(sB1, nf * 16 + lm, kc), a1[nf]);
            a2[nf] = MFMA(af, frag(sB2, nf * 16 + lm, kc), a2[nf]);
        }
    }
    size_t base = (((size_t)z * KK + k) * HH + c) * LL;
#pragma unroll
    for (int nf = 0; nf < 4; ++nf)
#pragma unroll
        for (int r = 0; r < 4; ++r) {
            int j = jt * 64 + w * 16 + lg * 4 + r;
            int a = nf * 16 + lm;
            M1Nb[(base + j) * DD + a] = f2b(a1[nf][r]);
            M2Nb[(base + j) * DD + a] = f2b(a2[nf][r]);
        }
}

// ---------------- K3: muxed {collapse 128 blk} {band 2048 blk} {qg 256 blk} ----------------
__global__ __launch_bounds__(256, 4) void k_collaux(const float* __restrict__ Qz,
        const ushort_t* __restrict__ M1Nb, const ushort_t* __restrict__ M2Nb,
        const float* __restrict__ dp, const float* __restrict__ gp, const int* __restrict__ mask,
        ushort_t* __restrict__ MPNb, ushort_t* __restrict__ MMNb,
        ushort_t* __restrict__ MP2Nb, ushort_t* __restrict__ MM2Nb,
        ushort_t* __restrict__ MPT, ushort_t* __restrict__ MMT,
        ushort_t* __restrict__ MP2T, ushort_t* __restrict__ MM2T,
        float* __restrict__ BAND, float* __restrict__ QG) {
    __shared__ __align__(16) ushort_t sT[4 * 64 * 65];
    int tid = threadIdx.x;
    int b = blockIdx.x;
    if (b < 128) {
        int jt = b & 7, zc = b >> 3;
        int z = zc >> 3, c = zc & 7;
        ushort_t* sP1 = sT;
        ushort_t* sM1 = sT + 64 * 65;
        ushort_t* sP2 = sT + 2 * 64 * 65;
        ushort_t* sM2 = sT + 3 * 64 * 65;
        float w4[4], w5[4];
#pragma unroll
        for (int k = 0; k < 4; ++k) { w4[k] = dp[12 + k]; w5[k] = dp[16 + k]; }
        size_t b0 = (((size_t)z * KK * HH + c) * LL + jt * 64) * DD;
        const size_t kstr = (size_t)HH * LL * DD;
        for (int g = tid; g < 512; g += 256) {
            int j = g >> 3, a0 = (g & 7) * 8;
            size_t o = b0 + (size_t)j * DD + a0;
            float p1[8] = {}, q1[8] = {}, p2[8] = {}, q2[8] = {};
#pragma unroll
            for (int k = 0; k < 4; ++k) {
                uint4 v1 = *reinterpret_cast<const uint4*>(&M1Nb[o + k * kstr]);
                uint4 v2 = *reinterpret_cast<const uint4*>(&M2Nb[o + k * kstr]);
                const ushort_t* s1 = reinterpret_cast<const ushort_t*>(&v1);
                const ushort_t* s2 = reinterpret_cast<const ushort_t*>(&v2);
#pragma unroll
                for (int u = 0; u < 8; ++u) {
                    float f1 = b2f(s1[u]), f2v = b2f(s2[u]);
                    p1[u] += w4[k] * f1; q1[u] += w5[k] * f1;
                    p2[u] += w4[k] * f2v; q2[u] += w5[k] * f2v;
                }
            }
            ushort_t t1[8], t2[8], t3[8], t4[8];
#pragma unroll
            for (int u = 0; u < 8; ++u) {
                t1[u] = f2b(p1[u]); t2[u] = f2b(q1[u]); t3[u] = f2b(p2[u]); t4[u] = f2b(q2[u]);
                sP1[(a0 + u) * 65 + j] = t1[u]; sM1[(a0 + u) * 65 + j] = t2[u];
                sP2[(a0 + u) * 65 + j] = t3[u]; sM2[(a0 + u) * 65 + j] = t4[u];
            }
            size_t on = ((size_t)zc * LL + jt * 64 + j) * DD + a0;
            *reinterpret_cast<uint4*>(&MPNb[on])  = *reinterpret_cast<uint4*>(t1);
            *reinterpret_cast<uint4*>(&MMNb[on])  = *reinterpret_cast<uint4*>(t2);
            *reinterpret_cast<uint4*>(&MP2Nb[on]) = *reinterpret_cast<uint4*>(t3);
            *reinterpret_cast<uint4*>(&MM2Nb[on]) = *reinterpret_cast<uint4*>(t4);
        }
        __syncthreads();
        for (int g = tid; g < 512; g += 256) {
            int a = g >> 3, j0 = (g & 7) * 8;
            ushort_t o1[8], o2[8], o3[8], o4[8];
#pragma unroll
            for (int u = 0; u < 8; ++u) {
                o1[u] = sP1[a * 65 + j0 + u]; o2[u] = sM1[a * 65 + j0 + u];
                o3[u] = sP2[a * 65 + j0 + u]; o4[u] = sM2[a * 65 + j0 + u];
            }
            size_t ot = ((size_t)zc * DD + a) * LL + jt * 64 + j0;
            *reinterpret_cast<uint4*>(&MPT[ot])  = *reinterpret_cast<uint4*>(o1);
            *reinterpret_cast<uint4*>(&MMT[ot])  = *reinterpret_cast<uint4*>(o2);
            *reinterpret_cast<uint4*>(&MP2T[ot]) = *reinterpret_cast<uint4*>(o3);
            *reinterpret_cast<uint4*>(&MM2T[ot]) = *reinterpret_cast<uint4*>(o4);
        }
    } else if (b < 2176) {
        int w = (b - 128) * 4 + (tid >> 6);
        int lane = tid & 63;
        int j = w & 511, c = (w >> 9) & 7, z = w >> 12;
        float m[4];
#pragma unroll
        for (int k = 0; k < 4; ++k)
            m[k] = b2f(M1Nb[((((size_t)z * KK + k) * HH + c) * LL + j) * DD + lane]);
        float out = 0.f;
#pragma unroll
        for (int d = -3; d <= 3; ++d) {
            int i = j + d;
            if (i < 0 || i >= LL) continue;
            int idx = d < 0 ? d + 9 : d;
            float t = 0.f;
            if (idx != 0) {
#pragma unroll
                for (int k = 0; k < 4; ++k) t += dp[(idx - 1) * 4 + k] * m[k];
            }
            float s = Qz[(z * LL + i) * DD + lane] * t;
#pragma unroll
            for (int o = 32; o > 0; o >>= 1) s += __shfl_xor(s, o, 64);
            if (lane == d + 3) out = s;
        }
        if (lane < 7) BAND[(size_t)w * 8 + lane] = out;
    } else {
        float* gpS = reinterpret_cast<float*>(sT);
#pragma unroll
        for (int idx = tid; idx < 4096; idx += 256) gpS[(idx >> 6) * 68 + (idx & 63)] = gp[idx];
        __syncthreads();
        int row = (b - 2176) * 4 + (tid >> 6);
        int g = tid & 63;
        float qv = Qz[row * DD + g];
        float s = 0.f;
#pragma unroll 8
        for (int a = 0; a < 64; ++a) s += __shfl(qv, a, 64) * gpS[g * 68 + a];
        if (mask[row] == 0) s = NEGV;
        float m = s;
#pragma unroll
        for (int o = 32; o > 0; o >>= 1) m = fmaxf(m, __shfl_xor(m, o, 64));
        float e = __expf(s - m);
        float sum = e;
#pragma unroll
        for (int o = 32; o > 0; o >>= 1) sum += __shfl_xor(sum, o, 64);
        QG[row * GG + g] = e / sum;
    }
}

// ---------------- K4: fused s_h MFMA + band + mask + row-softmax + dual bf16 write ----------------
// grid (8 it, 16 zc); block computes 64 rows x 512 cols of one head, softmaxes in-register,
// writes SHB [i][j] and SHBT [j][i] directly. SH fp32 never materialized.
__global__ __launch_bounds__(256, 2) void k_shsm(const ushort_t* __restrict__ QzB,
        const ushort_t* __restrict__ MPNb, const ushort_t* __restrict__ MMNb,
        const float* __restrict__ BAND, const int* __restrict__ mask,
        ushort_t* __restrict__ SHB, ushort_t* __restrict__ SHBT) {
    int it = blockIdx.x, zc = blockIdx.y;
    int z = zc >> 3;
    __shared__ ushort_t sA[4096], sB[4096];
    __shared__ ushort_t tl[64 * 72];
    int tid = threadIdx.x;
    int w = tid >> 6, lm = tid & 15, lg = (tid & 63) >> 4;
    stage64(sA, QzB + (size_t)(z * LL + it * 64) * DD, DD, tid);
    f32x4 acc[8][4];
#pragma unroll
    for (int jt = 0; jt < 8; ++jt)
#pragma unroll
        for (int nf = 0; nf < 4; ++nf) acc[jt][nf] = {0.f, 0.f, 0.f, 0.f};
#pragma unroll
    for (int jt = 0; jt < 8; ++jt) {
        bool diag = (it == jt);
        size_t bbase = ((size_t)zc * LL + jt * 64) * DD;
        const ushort_t* B0 = diag ? MPNb : (it > jt ? MPNb : MMNb);
        __syncthreads();
        stage64(sB, B0 + bbase, DD, tid);
        __syncthreads();
#pragma unroll
        for (int ks = 0; ks < 2; ++ks) {
            int kc = ks * 32 + lg * 8;
            bf16x8 af = frag(sA, w * 16 + lm, kc);
#pragma unroll
            for (int nf = 0; nf < 4; ++nf)
                acc[jt][nf] = MFMA(af, frag(sB, nf * 16 + lm, kc), acc[jt][nf]);
        }
        if (diag) {
            __syncthreads();
            stage64(sB, MMNb + bbase, DD, tid);
            __syncthreads();
            f32x4 accM[4];
#pragma unroll
            for (int nf = 0; nf < 4; ++nf) accM[nf] = {0.f, 0.f, 0.f, 0.f};
#pragma unroll
            for (int ks = 0; ks < 2; ++ks) {
                int kc = ks * 32 + lg * 8;
                bf16x8 af = frag(sA, w * 16 + lm, kc);
#pragma unroll
                for (int nf = 0; nf < 4; ++nf)
                    accM[nf] = MFMA(af, frag(sB, nf * 16 + lm, kc), accM[nf]);
            }
#pragma unroll
            for (int nf = 0; nf < 4; ++nf)
#pragma unroll
                for (int r = 0; r < 4; ++r) {
                    int i = it * 64 + w * 16 + lg * 4 + r;
                    int j = jt * 64 + nf * 16 + lm;
                    if (i <= j) acc[jt][nf][r] = accM[nf][r];
                }
        }
    }
    // band overwrite + mask
    int mi[4];
#pragma unroll
    for (int r = 0; r < 4; ++r) mi[r] = mask[z * LL + it * 64 + w * 16 + lg * 4 + r];
#pragma unroll
    for (int jt = 0; jt < 8; ++jt) {
#pragma unroll
        for (int nf = 0; nf < 4; ++nf) {
            int j = jt * 64 + nf * 16 + lm;
            int mjv = mask[z * LL + j];
#pragma unroll
            for (int r = 0; r < 4; ++r) {
                int i = it * 64 + w * 16 + lg * 4 + r;
                int d = i - j;
                float v = acc[jt][nf][r];
                if (d >= -3 && d <= 3) v = BAND[((size_t)zc * LL + j) * 8 + (d + 3)];
                if (!(mi[r] && mjv)) v = NEGV;
                acc[jt][nf][r] = v;
            }
        }
    }
    // row softmax: values for row (w*16+lg*4+r) live in this thread (32 of them) + 15 lane-mates (lm)
    float inv[4];
#pragma unroll
    for (int r = 0; r < 4; ++r) {
        float m = -1e30f;
#pragma unroll
        for (int jt = 0; jt < 8; ++jt)
#pragma unroll
            for (int nf = 0; nf < 4; ++nf) m = fmaxf(m, acc[jt][nf][r]);
#pragma unroll
        for (int o = 1; o < 16; o <<= 1) m = fmaxf(m, __shfl_xor(m, o, 64));
        float s = 0.f;
#pragma unroll
        for (int jt = 0; jt < 8; ++jt)
#pragma unroll
            for (int nf = 0; nf < 4; ++nf) {
                float e = __expf(acc[jt][nf][r] - m);
                acc[jt][nf][r] = e;
                s += e;
            }
#pragma unroll
        for (int o = 1; o < 16; o <<= 1) s += __shfl_xor(s, o, 64);
        inv[r] = 1.f / s;
    }
    // per-jt: bf16 tile -> LDS -> coalesced SHB + SHBT writes
#pragma unroll
    for (int jt = 0; jt < 8; ++jt) {
        __syncthreads();
#pragma unroll
        for (int nf = 0; nf < 4; ++nf)
#pragma unroll
            for (int r = 0; r < 4; ++r)
                tl[(w * 16 + lg * 4 + r) * 72 + nf * 16 + lm] = f2b(acc[jt][nf][r] * inv[r]);
        __syncthreads();
        for (int g = tid; g < 512; g += 256) {
            int row = g >> 3, c0 = (g & 7) * 8;
            ushort_t tmp[8];
#pragma unroll
            for (int u = 0; u < 8; ++u) tmp[u] = tl[row * 72 + c0 + u];
            *reinterpret_cast<uint4*>(
                &SHB[((size_t)zc * LL + it * 64 + row) * LL + jt * 64 + c0]) =
                *reinterpret_cast<uint4*>(tmp);
            ushort_t tmp2[8];
#pragma unroll
            for (int u = 0; u < 8; ++u) tmp2[u] = tl[(c0 + u) * 72 + row];
            *reinterpret_cast<uint4*>(
                &SHBT[((size_t)zc * LL + jt * 64 + row) * LL + it * 64 + c0]) =
                *reinterpret_cast<uint4*>(tmp2);
        }
    }
}

// ---------------- K5: muxed {g12 main GEMMs (512 blk)} {corr12 (1024 blk)} ----------------
__global__ __launch_bounds__(256, 4) void k_g12corr(const ushort_t* __restrict__ SHB,
        const ushort_t* __restrict__ SHBT,
        const ushort_t* __restrict__ MPT, const ushort_t* __restrict__ MMT,
        const ushort_t* __restrict__ MP2T, const ushort_t* __restrict__ MM2T,
        const ushort_t* __restrict__ M1Nb, const ushort_t* __restrict__ M2Nb,
        const ushort_t* __restrict__ MPNb, const ushort_t* __restrict__ MMNb,
        const ushort_t* __restrict__ MP2Nb, const ushort_t* __restrict__ MM2Nb,
        const float* __restrict__ dp, float* __restrict__ PG) {
    __shared__ ushort_t sSH[4096], sM[4096];
    int tid = threadIdx.x;
    int b = blockIdx.x;
    if (b < 512) {
        int it = b & 7, jc = (b >> 3) & 1, zcw = b >> 4;
        int which = zcw >> 4;
        int z = (zcw >> 3) & 1, c = zcw & 7;
        const ushort_t* Amat = which ? SHBT : SHB;
        const ushort_t* TP = which ? MP2T : MPT;
        const ushort_t* TM = which ? MM2T : MMT;
        int w = tid >> 6, lm = tid & 15, lg = (tid & 63) >> 4;
        f32x4 acc[4];
#pragma unroll
        for (int nf = 0; nf < 4; ++nf) acc[nf] = {0.f,0.f,0.f,0.f};
        size_t shbase = ((size_t)(z * HH + c) * LL + it * 64) * LL;
        size_t mbase  = ((size_t)(z * HH + c) * DD) * LL;
        for (int js = 0; js < 4; ++js) {
            int j0 = jc * 256 + js * 64;
            bool dg = (j0 == it * 64);
            bool useP = which == 0 ? (j0 < it * 64) : (j0 > it * 64);
            __syncthreads();
            stage64(sSH, Amat + shbase + j0, LL, tid);
            stage64(sM, (dg ? TP : (useP ? TP : TM)) + mbase + j0, LL, tid);
            __syncthreads();
            for (int pass = 0; pass < (dg ? 2 : 1); ++pass) {
                if (pass == 1) {
                    __syncthreads();
                    stage64(sM, TM + mbase + j0, LL, tid);
                    __syncthreads();
                }
#pragma unroll
                for (int ks = 0; ks < 2; ++ks) {
                    int kc = ks * 32 + lg * 8;
                    int jb = j0 + kc;
                    bf16x8 af = frag(sSH, w * 16 + lm, kc);
                    if (dg) {
                        int i = it * 64 + w * 16 + lm;
                        int cnt = (which == 0) ? iclamp(i - jb, 0, 8) : iclamp(i + 1 - jb, 0, 8);
                        af = maskfrag(af, cnt, (pass == 0) == (which == 0));
                    }
#pragma unroll
                    for (int nf = 0; nf < 4; ++nf)
                        acc[nf] = MFMA(af, frag(sM, nf * 16 + lm, kc), acc[nf]);
                }
            }
        }
        int slot = which * 16 + c * 2 + jc;
#pragma unroll
        for (int nf = 0; nf < 4; ++nf)
#pragma unroll
            for (int r = 0; r < 4; ++r) {
                int i = it * 64 + w * 16 + lg * 4 + r;
                int a = nf * 16 + lm;
                PG[((size_t)(slot * BB + z) * LL + i) * DD + a] = acc[nf][r];
            }
    } else {
        int bid = b - 512;
        int which = bid >> 9; bid &= 511;
        int w = bid * 4 + (tid >> 6);
        int lane = tid & 63;
        int ch = w & 1, i = (w >> 1) & 511, z = w >> 10;
        const ushort_t* Mx = which ? M2Nb : M1Nb;
        const ushort_t* MPb = which ? MP2Nb : MPNb;
        const ushort_t* MMb = which ? MM2Nb : MMNb;
        float acc = 0.f;
        for (int cc = 0; cc < 4; ++cc) {
            int c = ch * 4 + cc;
#pragma unroll
            for (int d = -3; d <= 3; ++d) {
                int j = which ? i + d : i - d;
                if (j < 0 || j >= LL) continue;
                float qh = which ? b2f(SHB[(((size_t)z * HH + c) * LL + j) * LL + i])
                                 : b2f(SHB[(((size_t)z * HH + c) * LL + i) * LL + j]);
                int idx = d < 0 ? d + 9 : d;
                float e = 0.f;
                if (idx != 0) {
#pragma unroll
                    for (int k = 0; k < 4; ++k)
                        e += dp[(idx - 1) * 4 + k] *
                             b2f(Mx[((((size_t)z * KK + k) * HH + c) * LL + j) * DD + lane]);
                }
                const ushort_t* mb = (d > 0) ? MPb : MMb;
                float mn = b2f(mb[(((size_t)z * HH + c) * LL + j) * DD + lane]);
                acc += qh * (e - mn);
            }
        }
        int slot = 32 + which * 2 + ch;
        PG[(((size_t)slot * BB + z) * LL + i) * DD + lane] = acc;
    }
}

// ---------------- K6: q_next = x + sum(NSLOT slots) + gg ----------------
__global__ __launch_bounds__(256) void k_update(const float* __restrict__ x, const float* __restrict__ PG,
                         const float* __restrict__ QG, const float* __restrict__ gp,
                         float* __restrict__ outq) {
    __shared__ __align__(16) float gpS[64][68];
    int tid = threadIdx.x;
#pragma unroll
    for (int idx = tid; idx < 4096; idx += 256) gpS[idx >> 6][idx & 63] = gp[idx];
    __syncthreads();
    int row = blockIdx.x * 4 + (tid >> 6);
    int a = tid & 63;
    float acc = x[row * DD + a];
    float qgv = QG[row * GG + a];
#pragma unroll 8
    for (int g = 0; g < 64; ++g) acc += __shfl(qgv, g, 64) * gpS[g][a];
#pragma unroll 6
    for (int s = 0; s < NSLOT; ++s) acc += PG[((size_t)s * BB * LL + row) * DD + a];
    outq[row * DD + a] = acc;
}

extern "C" void kernel_launch(void* const* d_in, const int* in_sizes, int n_in,
                              void* d_out, int out_size, void* d_ws, size_t ws_size,
                              hipStream_t stream) {
    const float* x    = (const float*)d_in[0];
    const int*   mask = (const int*)d_in[1];
    const float* dp   = (const float*)d_in[2];
    const float* T    = (const float*)d_in[3];
    const float* gp   = (const float*)d_in[4];
    float* out = (float*)d_out;

    float* p = (float*)d_ws;
    float* Qz = p;                        p += 65536;
    ushort_t* QzB = (ushort_t*)p;         p += 32768;
    ushort_t* TB1 = (ushort_t*)p;         p += 65536;
    ushort_t* TB2 = (ushort_t*)p;         p += 65536;
    ushort_t* M1Nb = (ushort_t*)p;        p += 1048576;
    ushort_t* M2Nb = (ushort_t*)p;        p += 1048576;
    ushort_t* MPNb  = (ushort_t*)p;       p += 262144;
    ushort_t* MMNb  = (ushort_t*)p;       p += 262144;
    ushort_t* MP2Nb = (ushort_t*)p;       p += 262144;
    ushort_t* MM2Nb = (ushort_t*)p;       p += 262144;
    ushort_t* MPT   = (ushort_t*)p;       p += 262144;
    ushort_t* MMT   = (ushort_t*)p;       p += 262144;
    ushort_t* MP2T  = (ushort_t*)p;       p += 262144;
    ushort_t* MM2T  = (ushort_t*)p;       p += 262144;
    float* BAND = p;                      p += 65536;
    ushort_t* SHB  = (ushort_t*)p;        p += 2097152;
    ushort_t* SHBT = (ushort_t*)p;        p += 2097152;
    float* QG   = p;                      p += 65536;
    float* PG   = p;                      p += (size_t)NSLOT * 65536;
    float* QZ1  = p;                      p += 65536;
    // total ~45 MB (SH fp32 dropped)

    hipLaunchKernelGGL(k_prepT, dim3(32), dim3(256), 0, stream, T, TB1, TB2);

    const float* qsrc = x;
    for (int iter = 0; iter < 2; ++iter) {
        float* qdst = (iter == 0) ? QZ1 : out;
        hipLaunchKernelGGL(k_softmax_qz, dim3(256), dim3(256), 0, stream, qsrc, Qz, QzB);
        hipLaunchKernelGGL(k_compute_M, dim3(8, 8, 8), dim3(256), 0, stream, QzB, TB1, TB2, M1Nb, M2Nb);
        hipLaunchKernelGGL(k_collaux, dim3(2432), dim3(256), 0, stream, Qz, M1Nb, M2Nb, dp, gp, mask,
                           MPNb, MMNb, MP2Nb, MM2Nb, MPT, MMT, MP2T, MM2T, BAND, QG);
        hipLaunchKernelGGL(k_shsm, dim3(8, 16), dim3(256), 0, stream, QzB, MPNb, MMNb, BAND, mask,
                           SHB, SHBT);
        hipLaunchKernelGGL(k_g12corr, dim3(1536), dim3(256), 0, stream, SHB, SHBT,
                           MPT, MMT, MP2T, MM2T, M1Nb, M2Nb,
                           MPNb, MMNb, MP2Nb, MM2Nb, dp, PG);
        hipLaunchKernelGGL(k_update, dim3(256), dim3(256), 0, stream, x, PG, QG, gp, qdst);
        qsrc = qdst;
    }
}

// Round 9
// 138.516 us; speedup vs baseline: 1.1463x; 1.1463x over previous
//
#include <hip/hip_runtime.h>

#define BB 2
#define LL 512
#define DD 64
#define HH 8
#define GG 64
#define KK 4
#define NEGV -1e9f
#define NSLOT 36

typedef unsigned short ushort_t;
typedef __attribute__((ext_vector_type(8))) short bf16x8;
typedef __attribute__((ext_vector_type(4))) float f32x4;
#define MFMA(a, b, c) __builtin_amdgcn_mfma_f32_16x16x32_bf16(a, b, c, 0, 0, 0)

__device__ __forceinline__ ushort_t f2b(float f) {
    unsigned int u = __float_as_uint(f);
    return (ushort_t)((u + 0x7FFFu + ((u >> 16) & 1u)) >> 16);
}
__device__ __forceinline__ float b2f(ushort_t s) {
    return __uint_as_float(((unsigned int)s) << 16);
}

// stage a 64x64 bf16 tile (row-major, rowstride elems) into LDS with granule-XOR swizzle
__device__ __forceinline__ void stage64(ushort_t* dst, const ushort_t* src,
                                        int rowstride, int tid) {
#pragma unroll
    for (int g = tid; g < 512; g += 256) {
        int row = g >> 3, colg = g & 7;
        uint4 v = *reinterpret_cast<const uint4*>(&src[row * rowstride + (colg << 3)]);
        *reinterpret_cast<uint4*>(&dst[(row << 6) + ((colg ^ (row & 7)) << 3)]) = v;
    }
}
// read an 8-elem fragment (col multiple of 8) from swizzled LDS tile
__device__ __forceinline__ bf16x8 frag(const ushort_t* s, int row, int col) {
    return *reinterpret_cast<const bf16x8*>(&s[(row << 6) + ((((col >> 3) ^ (row & 7))) << 3)]);
}
__device__ __forceinline__ bf16x8 maskfrag(bf16x8 v, int cnt, bool keep_prefix) {
    bf16x8 r;
#pragma unroll
    for (int u = 0; u < 8; ++u) {
        bool keep = keep_prefix ? (u < cnt) : (u >= cnt);
        r[u] = keep ? v[u] : (short)0;
    }
    return r;
}
__device__ __forceinline__ int iclamp(int v, int lo, int hi) {
    return v < lo ? lo : (v > hi ? hi : v);
}

// ---------------- K0 (once): T -> bf16 MFMA operand tiles ----------------
__global__ __launch_bounds__(256) void k_prepT(const float* __restrict__ T,
                                               ushort_t* __restrict__ TB1,
                                               ushort_t* __restrict__ TB2) {
    int k = blockIdx.x >> 3, c = blockIdx.x & 7;   // 32 blocks
    int tid = threadIdx.x;
    for (int g = tid; g < 512; g += 256) {
        int a = g >> 3, b0 = (g & 7) * 8;
        ushort_t o1[8], o2[8];
#pragma unroll
        for (int u = 0; u < 8; ++u) {
            o1[u] = f2b(T[(((k * 64 + a) * 64) + b0 + u) * 8 + c]);
            o2[u] = f2b(T[(((k * 64 + b0 + u) * 64) + a) * 8 + c]);
        }
        size_t base = ((size_t)(k * 8 + c) * 64 + a) * 64 + b0;
        *reinterpret_cast<uint4*>(&TB1[base]) = *reinterpret_cast<uint4*>(o1);
        *reinterpret_cast<uint4*>(&TB2[base]) = *reinterpret_cast<uint4*>(o2);
    }
}

// ---------------- K1: Q_z = softmax(q_z) over d=64; fp32 + bf16 outputs ----------------
__global__ __launch_bounds__(256) void k_softmax_qz(const float* __restrict__ src,
                                                    float* __restrict__ Qz,
                                                    ushort_t* __restrict__ QzB) {
    int row = blockIdx.x * 4 + (threadIdx.x >> 6);
    int lane = threadIdx.x & 63;
    float v = src[row * DD + lane];
    float m = v;
#pragma unroll
    for (int o = 32; o > 0; o >>= 1) m = fmaxf(m, __shfl_xor(m, o, 64));
    float e = __expf(v - m);
    float s = e;
#pragma unroll
    for (int o = 32; o > 0; o >>= 1) s += __shfl_xor(s, o, 64);
    float r = e / s;
    Qz[row * DD + lane] = r;
    QzB[row * DD + lane] = f2b(r);
}

// ---------------- K2: M1/M2 via MFMA ----------------
__global__ __launch_bounds__(256) void k_compute_M(const ushort_t* __restrict__ QzB,
        const ushort_t* __restrict__ TB1, const ushort_t* __restrict__ TB2,
        ushort_t* __restrict__ M1Nb, ushort_t* __restrict__ M2Nb) {
    int jt = blockIdx.x, c = blockIdx.y;
    int z = blockIdx.z >> 2, k = blockIdx.z & 3;
    __shared__ ushort_t sQ[4096], sB1[4096], sB2[4096];
    int tid = threadIdx.x;
    stage64(sQ, QzB + (size_t)(z * LL + jt * 64) * DD, DD, tid);
    size_t tb = (size_t)(k * 8 + c) * 4096;
    stage64(sB1, TB1 + tb, 64, tid);
    stage64(sB2, TB2 + tb, 64, tid);
    __syncthreads();
    int w = tid >> 6, lm = tid & 15, lg = (tid & 63) >> 4;
    f32x4 a1[4], a2[4];
#pragma unroll
    for (int nf = 0; nf < 4; ++nf) { a1[nf] = {0.f,0.f,0.f,0.f}; a2[nf] = {0.f,0.f,0.f,0.f}; }
#pragma unroll
    for (int ks = 0; ks < 2; ++ks) {
        int kc = ks * 32 + lg * 8;
        bf16x8 af = frag(sQ, w * 16 + lm, kc);
#pragma unroll
        for (int nf = 0; nf < 4; ++nf) {
            a1[nf] = MFMA(af, frag(sB1, nf * 16 + lm, kc), a1[nf]);
            a2[nf] = MFMA(af, frag(sB2, nf * 16 + lm, kc), a2[nf]);
        }
    }
    size_t base = (((size_t)z * KK + k) * HH + c) * LL;
#pragma unroll
    for (int nf = 0; nf < 4; ++nf)
#pragma unroll
        for (int r = 0; r < 4; ++r) {
            int j = jt * 64 + w * 16 + lg * 4 + r;
            int a = nf * 16 + lm;
            M1Nb[(base + j) * DD + a] = f2b(a1[nf][r]);
            M2Nb[(base + j) * DD + a] = f2b(a2[nf][r]);
        }
}

// ---------------- K3: muxed {collapse 128 blk} {band 2048 blk} {qg 256 blk} ----------------
__global__ __launch_bounds__(256, 4) void k_collaux(const float* __restrict__ Qz,
        const ushort_t* __restrict__ M1Nb, const ushort_t* __restrict__ M2Nb,
        const float* __restrict__ dp, const float* __restrict__ gp, const int* __restrict__ mask,
        ushort_t* __restrict__ MPNb, ushort_t* __restrict__ MMNb,
        ushort_t* __restrict__ MP2Nb, ushort_t* __restrict__ MM2Nb,
        ushort_t* __restrict__ MPT, ushort_t* __restrict__ MMT,
        ushort_t* __restrict__ MP2T, ushort_t* __restrict__ MM2T,
        float* __restrict__ BAND, float* __restrict__ QG) {
    __shared__ __align__(16) ushort_t sT[4 * 64 * 65];
    int tid = threadIdx.x;
    int b = blockIdx.x;
    if (b < 128) {
        int jt = b & 7, zc = b >> 3;
        int z = zc >> 3, c = zc & 7;
        ushort_t* sP1 = sT;
        ushort_t* sM1 = sT + 64 * 65;
        ushort_t* sP2 = sT + 2 * 64 * 65;
        ushort_t* sM2 = sT + 3 * 64 * 65;
        float w4[4], w5[4];
#pragma unroll
        for (int k = 0; k < 4; ++k) { w4[k] = dp[12 + k]; w5[k] = dp[16 + k]; }
        size_t b0 = (((size_t)z * KK * HH + c) * LL + jt * 64) * DD;
        const size_t kstr = (size_t)HH * LL * DD;
        for (int g = tid; g < 512; g += 256) {
            int j = g >> 3, a0 = (g & 7) * 8;
            size_t o = b0 + (size_t)j * DD + a0;
            float p1[8] = {}, q1[8] = {}, p2[8] = {}, q2[8] = {};
#pragma unroll
            for (int k = 0; k < 4; ++k) {
                uint4 v1 = *reinterpret_cast<const uint4*>(&M1Nb[o + k * kstr]);
                uint4 v2 = *reinterpret_cast<const uint4*>(&M2Nb[o + k * kstr]);
                const ushort_t* s1 = reinterpret_cast<const ushort_t*>(&v1);
                const ushort_t* s2 = reinterpret_cast<const ushort_t*>(&v2);
#pragma unroll
                for (int u = 0; u < 8; ++u) {
                    float f1 = b2f(s1[u]), f2v = b2f(s2[u]);
                    p1[u] += w4[k] * f1; q1[u] += w5[k] * f1;
                    p2[u] += w4[k] * f2v; q2[u] += w5[k] * f2v;
                }
            }
            ushort_t t1[8], t2[8], t3[8], t4[8];
#pragma unroll
            for (int u = 0; u < 8; ++u) {
                t1[u] = f2b(p1[u]); t2[u] = f2b(q1[u]); t3[u] = f2b(p2[u]); t4[u] = f2b(q2[u]);
                sP1[(a0 + u) * 65 + j] = t1[u]; sM1[(a0 + u) * 65 + j] = t2[u];
                sP2[(a0 + u) * 65 + j] = t3[u]; sM2[(a0 + u) * 65 + j] = t4[u];
            }
            size_t on = ((size_t)zc * LL + jt * 64 + j) * DD + a0;
            *reinterpret_cast<uint4*>(&MPNb[on])  = *reinterpret_cast<uint4*>(t1);
            *reinterpret_cast<uint4*>(&MMNb[on])  = *reinterpret_cast<uint4*>(t2);
            *reinterpret_cast<uint4*>(&MP2Nb[on]) = *reinterpret_cast<uint4*>(t3);
            *reinterpret_cast<uint4*>(&MM2Nb[on]) = *reinterpret_cast<uint4*>(t4);
        }
        __syncthreads();
        for (int g = tid; g < 512; g += 256) {
            int a = g >> 3, j0 = (g & 7) * 8;
            ushort_t o1[8], o2[8], o3[8], o4[8];
#pragma unroll
            for (int u = 0; u < 8; ++u) {
                o1[u] = sP1[a * 65 + j0 + u]; o2[u] = sM1[a * 65 + j0 + u];
                o3[u] = sP2[a * 65 + j0 + u]; o4[u] = sM2[a * 65 + j0 + u];
            }
            size_t ot = ((size_t)zc * DD + a) * LL + jt * 64 + j0;
            *reinterpret_cast<uint4*>(&MPT[ot])  = *reinterpret_cast<uint4*>(o1);
            *reinterpret_cast<uint4*>(&MMT[ot])  = *reinterpret_cast<uint4*>(o2);
            *reinterpret_cast<uint4*>(&MP2T[ot]) = *reinterpret_cast<uint4*>(o3);
            *reinterpret_cast<uint4*>(&MM2T[ot]) = *reinterpret_cast<uint4*>(o4);
        }
    } else if (b < 2176) {
        int w = (b - 128) * 4 + (tid >> 6);
        int lane = tid & 63;
        int j = w & 511, c = (w >> 9) & 7, z = w >> 12;
        float m[4];
#pragma unroll
        for (int k = 0; k < 4; ++k)
            m[k] = b2f(M1Nb[((((size_t)z * KK + k) * HH + c) * LL + j) * DD + lane]);
        float out = 0.f;
#pragma unroll
        for (int d = -3; d <= 3; ++d) {
            int i = j + d;
            if (i < 0 || i >= LL) continue;
            int idx = d < 0 ? d + 9 : d;
            float t = 0.f;
            if (idx != 0) {
#pragma unroll
                for (int k = 0; k < 4; ++k) t += dp[(idx - 1) * 4 + k] * m[k];
            }
            float s = Qz[(z * LL + i) * DD + lane] * t;
#pragma unroll
            for (int o = 32; o > 0; o >>= 1) s += __shfl_xor(s, o, 64);
            if (lane == d + 3) out = s;
        }
        if (lane < 7) BAND[(size_t)w * 8 + lane] = out;
    } else {
        float* gpS = reinterpret_cast<float*>(sT);
#pragma unroll
        for (int idx = tid; idx < 4096; idx += 256) gpS[(idx >> 6) * 68 + (idx & 63)] = gp[idx];
        __syncthreads();
        int row = (b - 2176) * 4 + (tid >> 6);
        int g = tid & 63;
        float qv = Qz[row * DD + g];
        float s = 0.f;
#pragma unroll 8
        for (int a = 0; a < 64; ++a) s += __shfl(qv, a, 64) * gpS[g * 68 + a];
        if (mask[row] == 0) s = NEGV;
        float m = s;
#pragma unroll
        for (int o = 32; o > 0; o >>= 1) m = fmaxf(m, __shfl_xor(m, o, 64));
        float e = __expf(s - m);
        float sum = e;
#pragma unroll
        for (int o = 32; o > 0; o >>= 1) sum += __shfl_xor(sum, o, 64);
        QG[row * GG + g] = e / sum;
    }
}

// ---------------- K4: fused s_h MFMA + band + mask + row-softmax + dual bf16 write ----------------
// 32-row blocks: grid (16 ih, 16 zc) = 256 blocks. 4 waves in 2x2 layout:
// rw = row-half (16 rows), cw = col-half (4 jt tiles of 8).
__global__ __launch_bounds__(256, 2) void k_shsm32(const ushort_t* __restrict__ QzB,
        const ushort_t* __restrict__ MPNb, const ushort_t* __restrict__ MMNb,
        const float* __restrict__ BAND, const int* __restrict__ mask,
        ushort_t* __restrict__ SHB, ushort_t* __restrict__ SHBT) {
    int ih = blockIdx.x, zc = blockIdx.y;
    int it = ih >> 1, rh = ih & 1;
    int z = zc >> 3;
    int R0 = it * 64 + rh * 32;
    __shared__ ushort_t sA[2048];                 // 32x64
    __shared__ ushort_t sB0[4096], sB1[4096], sBd[4096];
    __shared__ ushort_t tl[2][32 * 72];
    __shared__ float redA[2][32], redB[2][32];
    int tid = threadIdx.x;
    int w = tid >> 6, lm = tid & 15, lg = (tid & 63) >> 4;
    int rw = w & 1, cw = w >> 1;
    // stage A: 32 rows x 64, 256 granules, one per thread
    {
        int row = tid >> 3, colg = tid & 7;
        uint4 v = *reinterpret_cast<const uint4*>(
            &QzB[(size_t)(z * LL + R0 + row) * DD + (colg << 3)]);
        *reinterpret_cast<uint4*>(&sA[(row << 6) + ((colg ^ (row & 7)) << 3)]) = v;
    }
    f32x4 acc[4][4];
#pragma unroll
    for (int jl = 0; jl < 4; ++jl)
#pragma unroll
        for (int nf = 0; nf < 4; ++nf) acc[jl][nf] = {0.f, 0.f, 0.f, 0.f};
    int dstep = it & 3;
#pragma unroll
    for (int s = 0; s < 4; ++s) {
        __syncthreads();
        int jt0 = s, jt1 = 4 + s;
        const ushort_t* src0 = (it >= jt0) ? MPNb : MMNb;   // it==jt0 handled via dual pass
        const ushort_t* src1 = (it >= jt1) ? MPNb : MMNb;
        stage64(sB0, src0 + ((size_t)zc * LL + jt0 * 64) * DD, DD, tid);
        stage64(sB1, src1 + ((size_t)zc * LL + jt1 * 64) * DD, DD, tid);
        if (s == dstep)
            stage64(sBd, MMNb + ((size_t)zc * LL + it * 64) * DD, DD, tid);
        __syncthreads();
        int jtg = cw ? jt1 : jt0;
        const ushort_t* sBx = cw ? sB1 : sB0;
#pragma unroll
        for (int ks = 0; ks < 2; ++ks) {
            int kc = ks * 32 + lg * 8;
            bf16x8 af = frag(sA, rw * 16 + lm, kc);
#pragma unroll
            for (int nf = 0; nf < 4; ++nf)
                acc[s][nf] = MFMA(af, frag(sBx, nf * 16 + lm, kc), acc[s][nf]);
        }
        if (jtg == it) {
            f32x4 accM[4];
#pragma unroll
            for (int nf = 0; nf < 4; ++nf) accM[nf] = {0.f, 0.f, 0.f, 0.f};
#pragma unroll
            for (int ks = 0; ks < 2; ++ks) {
                int kc = ks * 32 + lg * 8;
                bf16x8 af = frag(sA, rw * 16 + lm, kc);
#pragma unroll
                for (int nf = 0; nf < 4; ++nf)
                    accM[nf] = MFMA(af, frag(sBd, nf * 16 + lm, kc), accM[nf]);
            }
#pragma unroll
            for (int nf = 0; nf < 4; ++nf)
#pragma unroll
                for (int r = 0; r < 4; ++r) {
                    int i = R0 + rw * 16 + lg * 4 + r;
                    int j = it * 64 + nf * 16 + lm;
                    if (i <= j) acc[s][nf][r] = accM[nf][r];
                }
        }
    }
    // band overwrite + mask
    int mi[4];
#pragma unroll
    for (int r = 0; r < 4; ++r) mi[r] = mask[z * LL + R0 + rw * 16 + lg * 4 + r];
#pragma unroll
    for (int jl = 0; jl < 4; ++jl) {
        int jtg = cw * 4 + jl;
#pragma unroll
        for (int nf = 0; nf < 4; ++nf) {
            int j = jtg * 64 + nf * 16 + lm;
            int mjv = mask[z * LL + j];
#pragma unroll
            for (int r = 0; r < 4; ++r) {
                int i = R0 + rw * 16 + lg * 4 + r;
                int d = i - j;
                float v = acc[jl][nf][r];
                if (d >= -3 && d <= 3) v = BAND[((size_t)zc * LL + j) * 8 + (d + 3)];
                if (!(mi[r] && mjv)) v = NEGV;
                acc[jl][nf][r] = v;
            }
        }
    }
    // row softmax: 16 in-thread vals per r + 16-lane group + partner col-half wave
    float gm[4], gs[4], inv[4];
#pragma unroll
    for (int r = 0; r < 4; ++r) {
        float m = -1e30f;
#pragma unroll
        for (int jl = 0; jl < 4; ++jl)
#pragma unroll
            for (int nf = 0; nf < 4; ++nf) m = fmaxf(m, acc[jl][nf][r]);
#pragma unroll
        for (int o = 1; o < 16; o <<= 1) m = fmaxf(m, __shfl_xor(m, o, 64));
        gm[r] = m;
    }
    if (lm == 0) {
#pragma unroll
        for (int r = 0; r < 4; ++r) redA[cw][rw * 16 + lg * 4 + r] = gm[r];
    }
    __syncthreads();
#pragma unroll
    for (int r = 0; r < 4; ++r)
        gm[r] = fmaxf(gm[r], redA[cw ^ 1][rw * 16 + lg * 4 + r]);
#pragma unroll
    for (int r = 0; r < 4; ++r) {
        float s = 0.f;
#pragma unroll
        for (int jl = 0; jl < 4; ++jl)
#pragma unroll
            for (int nf = 0; nf < 4; ++nf) {
                float e = __expf(acc[jl][nf][r] - gm[r]);
                acc[jl][nf][r] = e;
                s += e;
            }
#pragma unroll
        for (int o = 1; o < 16; o <<= 1) s += __shfl_xor(s, o, 64);
        gs[r] = s;
    }
    if (lm == 0) {
#pragma unroll
        for (int r = 0; r < 4; ++r) redB[cw][rw * 16 + lg * 4 + r] = gs[r];
    }
    __syncthreads();
#pragma unroll
    for (int r = 0; r < 4; ++r)
        inv[r] = 1.f / (gs[r] + redB[cw ^ 1][rw * 16 + lg * 4 + r]);
    // per-jl: bf16 tiles (both col-halves) -> LDS -> coalesced SHB + SHBT writes
#pragma unroll
    for (int jl = 0; jl < 4; ++jl) {
        __syncthreads();
#pragma unroll
        for (int nf = 0; nf < 4; ++nf)
#pragma unroll
            for (int r = 0; r < 4; ++r)
                tl[cw][(rw * 16 + lg * 4 + r) * 72 + nf * 16 + lm] =
                    f2b(acc[jl][nf][r] * inv[r]);
        __syncthreads();
#pragma unroll
        for (int g = tid; g < 512; g += 256) {
            int cwg = g >> 8, rem = g & 255;
            int jtg = cwg * 4 + jl;
            int i_loc = rem >> 3, gj = rem & 7;
            ushort_t tmp[8];
#pragma unroll
            for (int u = 0; u < 8; ++u) tmp[u] = tl[cwg][i_loc * 72 + gj * 8 + u];
            *reinterpret_cast<uint4*>(
                &SHB[((size_t)zc * LL + R0 + i_loc) * LL + jtg * 64 + gj * 8]) =
                *reinterpret_cast<uint4*>(tmp);
        }
#pragma unroll
        for (int g = tid; g < 512; g += 256) {
            int cwg = g >> 8, rem = g & 255;
            int jtg = cwg * 4 + jl;
            int j_loc = rem >> 2, gi = rem & 3;
            ushort_t tmp2[8];
#pragma unroll
            for (int u = 0; u < 8; ++u) tmp2[u] = tl[cwg][(gi * 8 + u) * 72 + j_loc];
            *reinterpret_cast<uint4*>(
                &SHBT[((size_t)zc * LL + jtg * 64 + j_loc) * LL + R0 + gi * 8]) =
                *reinterpret_cast<uint4*>(tmp2);
        }
    }
}

// ---------------- K5: muxed {g12 main GEMMs (512 blk)} {corr12 (1024 blk)} ----------------
__global__ __launch_bounds__(256, 4) void k_g12corr(const ushort_t* __restrict__ SHB,
        const ushort_t* __restrict__ SHBT,
        const ushort_t* __restrict__ MPT, const ushort_t* __restrict__ MMT,
        const ushort_t* __restrict__ MP2T, const ushort_t* __restrict__ MM2T,
        const ushort_t* __restrict__ M1Nb, const ushort_t* __restrict__ M2Nb,
        const ushort_t* __restrict__ MPNb, const ushort_t* __restrict__ MMNb,
        const ushort_t* __restrict__ MP2Nb, const ushort_t* __restrict__ MM2Nb,
        const float* __restrict__ dp, float* __restrict__ PG) {
    __shared__ ushort_t sSH[4096], sM[4096];
    int tid = threadIdx.x;
    int b = blockIdx.x;
    if (b < 512) {
        int it = b & 7, jc = (b >> 3) & 1, zcw = b >> 4;
        int which = zcw >> 4;
        int z = (zcw >> 3) & 1, c = zcw & 7;
        const ushort_t* Amat = which ? SHBT : SHB;
        const ushort_t* TP = which ? MP2T : MPT;
        const ushort_t* TM = which ? MM2T : MMT;
        int w = tid >> 6, lm = tid & 15, lg = (tid & 63) >> 4;
        f32x4 acc[4];
#pragma unroll
        for (int nf = 0; nf < 4; ++nf) acc[nf] = {0.f,0.f,0.f,0.f};
        size_t shbase = ((size_t)(z * HH + c) * LL + it * 64) * LL;
        size_t mbase  = ((size_t)(z * HH + c) * DD) * LL;
        for (int js = 0; js < 4; ++js) {
            int j0 = jc * 256 + js * 64;
            bool dg = (j0 == it * 64);
            bool useP = which == 0 ? (j0 < it * 64) : (j0 > it * 64);
            __syncthreads();
            stage64(sSH, Amat + shbase + j0, LL, tid);
            stage64(sM, (dg ? TP : (useP ? TP : TM)) + mbase + j0, LL, tid);
            __syncthreads();
            for (int pass = 0; pass < (dg ? 2 : 1); ++pass) {
                if (pass == 1) {
                    __syncthreads();
                    stage64(sM, TM + mbase + j0, LL, tid);
                    __syncthreads();
                }
#pragma unroll
                for (int ks = 0; ks < 2; ++ks) {
                    int kc = ks * 32 + lg * 8;
                    int jb = j0 + kc;
                    bf16x8 af = frag(sSH, w * 16 + lm, kc);
                    if (dg) {
                        int i = it * 64 + w * 16 + lm;
                        int cnt = (which == 0) ? iclamp(i - jb, 0, 8) : iclamp(i + 1 - jb, 0, 8);
                        af = maskfrag(af, cnt, (pass == 0) == (which == 0));
                    }
#pragma unroll
                    for (int nf = 0; nf < 4; ++nf)
                        acc[nf] = MFMA(af, frag(sM, nf * 16 + lm, kc), acc[nf]);
                }
            }
        }
        int slot = which * 16 + c * 2 + jc;
#pragma unroll
        for (int nf = 0; nf < 4; ++nf)
#pragma unroll
            for (int r = 0; r < 4; ++r) {
                int i = it * 64 + w * 16 + lg * 4 + r;
                int a = nf * 16 + lm;
                PG[((size_t)(slot * BB + z) * LL + i) * DD + a] = acc[nf][r];
            }
    } else {
        int bid = b - 512;
        int which = bid >> 9; bid &= 511;
        int w = bid * 4 + (tid >> 6);
        int lane = tid & 63;
        int ch = w & 1, i = (w >> 1) & 511, z = w >> 10;
        const ushort_t* Mx = which ? M2Nb : M1Nb;
        const ushort_t* MPb = which ? MP2Nb : MPNb;
        const ushort_t* MMb = which ? MM2Nb : MMNb;
        float acc = 0.f;
        for (int cc = 0; cc < 4; ++cc) {
            int c = ch * 4 + cc;
#pragma unroll
            for (int d = -3; d <= 3; ++d) {
                int j = which ? i + d : i - d;
                if (j < 0 || j >= LL) continue;
                float qh = which ? b2f(SHB[(((size_t)z * HH + c) * LL + j) * LL + i])
                                 : b2f(SHB[(((size_t)z * HH + c) * LL + i) * LL + j]);
                int idx = d < 0 ? d + 9 : d;
                float e = 0.f;
                if (idx != 0) {
#pragma unroll
                    for (int k = 0; k < 4; ++k)
                        e += dp[(idx - 1) * 4 + k] *
                             b2f(Mx[((((size_t)z * KK + k) * HH + c) * LL + j) * DD + lane]);
                }
                const ushort_t* mb = (d > 0) ? MPb : MMb;
                float mn = b2f(mb[(((size_t)z * HH + c) * LL + j) * DD + lane]);
                acc += qh * (e - mn);
            }
        }
        int slot = 32 + which * 2 + ch;
        PG[(((size_t)slot * BB + z) * LL + i) * DD + lane] = acc;
    }
}

// ---------------- K6: q_next = x + sum(NSLOT slots) + gg ----------------
__global__ __launch_bounds__(256) void k_update(const float* __restrict__ x, const float* __restrict__ PG,
                         const float* __restrict__ QG, const float* __restrict__ gp,
                         float* __restrict__ outq) {
    __shared__ __align__(16) float gpS[64][68];
    int tid = threadIdx.x;
#pragma unroll
    for (int idx = tid; idx < 4096; idx += 256) gpS[idx >> 6][idx & 63] = gp[idx];
    __syncthreads();
    int row = blockIdx.x * 4 + (tid >> 6);
    int a = tid & 63;
    float acc = x[row * DD + a];
    float qgv = QG[row * GG + a];
#pragma unroll 8
    for (int g = 0; g < 64; ++g) acc += __shfl(qgv, g, 64) * gpS[g][a];
#pragma unroll 6
    for (int s = 0; s < NSLOT; ++s) acc += PG[((size_t)s * BB * LL + row) * DD + a];
    outq[row * DD + a] = acc;
}

extern "C" void kernel_launch(void* const* d_in, const int* in_sizes, int n_in,
                              void* d_out, int out_size, void* d_ws, size_t ws_size,
                              hipStream_t stream) {
    const float* x    = (const float*)d_in[0];
    const int*   mask = (const int*)d_in[1];
    const float* dp   = (const float*)d_in[2];
    const float* T    = (const float*)d_in[3];
    const float* gp   = (const float*)d_in[4];
    float* out = (float*)d_out;

    float* p = (float*)d_ws;
    float* Qz = p;                        p += 65536;
    ushort_t* QzB = (ushort_t*)p;         p += 32768;
    ushort_t* TB1 = (ushort_t*)p;         p += 65536;
    ushort_t* TB2 = (ushort_t*)p;         p += 65536;
    ushort_t* M1Nb = (ushort_t*)p;        p += 1048576;
    ushort_t* M2Nb = (ushort_t*)p;        p += 1048576;
    ushort_t* MPNb  = (ushort_t*)p;       p += 262144;
    ushort_t* MMNb  = (ushort_t*)p;       p += 262144;
    ushort_t* MP2Nb = (ushort_t*)p;       p += 262144;
    ushort_t* MM2Nb = (ushort_t*)p;       p += 262144;
    ushort_t* MPT   = (ushort_t*)p;       p += 262144;
    ushort_t* MMT   = (ushort_t*)p;       p += 262144;
    ushort_t* MP2T  = (ushort_t*)p;       p += 262144;
    ushort_t* MM2T  = (ushort_t*)p;       p += 262144;
    float* BAND = p;                      p += 65536;
    ushort_t* SHB  = (ushort_t*)p;        p += 2097152;
    ushort_t* SHBT = (ushort_t*)p;        p += 2097152;
    float* QG   = p;                      p += 65536;
    float* PG   = p;                      p += (size_t)NSLOT * 65536;
    float* QZ1  = p;                      p += 65536;

    hipLaunchKernelGGL(k_prepT, dim3(32), dim3(256), 0, stream, T, TB1, TB2);

    const float* qsrc = x;
    for (int iter = 0; iter < 2; ++iter) {
        float* qdst = (iter == 0) ? QZ1 : out;
        hipLaunchKernelGGL(k_softmax_qz, dim3(256), dim3(256), 0, stream, qsrc, Qz, QzB);
        hipLaunchKernelGGL(k_compute_M, dim3(8, 8, 8), dim3(256), 0, stream, QzB, TB1, TB2, M1Nb, M2Nb);
        hipLaunchKernelGGL(k_collaux, dim3(2432), dim3(256), 0, stream, Qz, M1Nb, M2Nb, dp, gp, mask,
                           MPNb, MMNb, MP2Nb, MM2Nb, MPT, MMT, MP2T, MM2T, BAND, QG);
        hipLaunchKernelGGL(k_shsm32, dim3(16, 16), dim3(256), 0, stream, QzB, MPNb, MMNb, BAND, mask,
                           SHB, SHBT);
        hipLaunchKernelGGL(k_g12corr, dim3(1536), dim3(256), 0, stream, SHB, SHBT,
                           MPT, MMT, MP2T, MM2T, M1Nb, M2Nb,
                           MPNb, MMNb, MP2Nb, MM2Nb, dp, PG);
        hipLaunchKernelGGL(k_update, dim3(256), dim3(256), 0, stream, x, PG, QG, gp, qdst);
        qsrc = qdst;
    }
}

// Round 10
// 134.352 us; speedup vs baseline: 1.1818x; 1.0310x over previous
//
#include <hip/hip_runtime.h>

#define BB 2
#define LL 512
#define DD 64
#define HH 8
#define GG 64
#define KK 4
#define NEGV -1e9f
#define NSLOT 36

typedef unsigned short ushort_t;
typedef __attribute__((ext_vector_type(8))) short bf16x8;
typedef __attribute__((ext_vector_type(4))) float f32x4;
#define MFMA(a, b, c) __builtin_amdgcn_mfma_f32_16x16x32_bf16(a, b, c, 0, 0, 0)

typedef const __attribute__((address_space(1))) unsigned int* gptr_t;
typedef __attribute__((address_space(3))) unsigned int* lptr_t;

__device__ __forceinline__ ushort_t f2b(float f) {
    unsigned int u = __float_as_uint(f);
    return (ushort_t)((u + 0x7FFFu + ((u >> 16) & 1u)) >> 16);
}
__device__ __forceinline__ float b2f(ushort_t s) {
    return __uint_as_float(((unsigned int)s) << 16);
}

// async global->LDS 16B: LDS dest = wave-uniform base + lane*16
__device__ __forceinline__ void gll16(const ushort_t* g, const ushort_t* l) {
    __builtin_amdgcn_global_load_lds(
        (gptr_t)(unsigned long long)g,
        (lptr_t)(unsigned int)(unsigned long long)l,
        16, 0, 0);
}

// async-stage a 64x64 bf16 tile: LDS linear, global source pre-XOR-swizzled.
// LDS[row][cg] = src[row][cg ^ (row&7)]; frag() applies the same XOR on read.
__device__ __forceinline__ void stage64a(ushort_t* dst, const ushort_t* src,
                                         int rowstride, int tid) {
    int lane = tid & 63, w = tid >> 6;
#pragma unroll
    for (int h = 0; h < 2; ++h) {
        int g = h * 256 + w * 64 + lane;
        int row = g >> 3, colg = g & 7;
        gll16(src + (size_t)row * rowstride + ((colg ^ (row & 7)) << 3),
              dst + (size_t)(h * 256 + w * 64) * 8);
    }
}
// read an 8-elem fragment (col multiple of 8) from swizzled LDS tile
__device__ __forceinline__ bf16x8 frag(const ushort_t* s, int row, int col) {
    return *reinterpret_cast<const bf16x8*>(&s[(row << 6) + ((((col >> 3) ^ (row & 7))) << 3)]);
}
__device__ __forceinline__ bf16x8 maskfrag(bf16x8 v, int cnt, bool keep_prefix) {
    bf16x8 r;
#pragma unroll
    for (int u = 0; u < 8; ++u) {
        bool keep = keep_prefix ? (u < cnt) : (u >= cnt);
        r[u] = keep ? v[u] : (short)0;
    }
    return r;
}
__device__ __forceinline__ int iclamp(int v, int lo, int hi) {
    return v < lo ? lo : (v > hi ? hi : v);
}

// ---------------- K0 (once): T -> bf16 MFMA operand tiles ----------------
__global__ __launch_bounds__(256) void k_prepT(const float* __restrict__ T,
                                               ushort_t* __restrict__ TB1,
                                               ushort_t* __restrict__ TB2) {
    int k = blockIdx.x >> 3, c = blockIdx.x & 7;   // 32 blocks
    int tid = threadIdx.x;
    for (int g = tid; g < 512; g += 256) {
        int a = g >> 3, b0 = (g & 7) * 8;
        ushort_t o1[8], o2[8];
#pragma unroll
        for (int u = 0; u < 8; ++u) {
            o1[u] = f2b(T[(((k * 64 + a) * 64) + b0 + u) * 8 + c]);
            o2[u] = f2b(T[(((k * 64 + b0 + u) * 64) + a) * 8 + c]);
        }
        size_t base = ((size_t)(k * 8 + c) * 64 + a) * 64 + b0;
        *reinterpret_cast<uint4*>(&TB1[base]) = *reinterpret_cast<uint4*>(o1);
        *reinterpret_cast<uint4*>(&TB2[base]) = *reinterpret_cast<uint4*>(o2);
    }
}

// ---------------- K1: Q_z = softmax(q_z) over d=64; fp32 + bf16 outputs ----------------
__global__ __launch_bounds__(256) void k_softmax_qz(const float* __restrict__ src,
                                                    float* __restrict__ Qz,
                                                    ushort_t* __restrict__ QzB) {
    int row = blockIdx.x * 4 + (threadIdx.x >> 6);
    int lane = threadIdx.x & 63;
    float v = src[row * DD + lane];
    float m = v;
#pragma unroll
    for (int o = 32; o > 0; o >>= 1) m = fmaxf(m, __shfl_xor(m, o, 64));
    float e = __expf(v - m);
    float s = e;
#pragma unroll
    for (int o = 32; o > 0; o >>= 1) s += __shfl_xor(s, o, 64);
    float r = e / s;
    Qz[row * DD + lane] = r;
    QzB[row * DD + lane] = f2b(r);
}

// ---------------- K2: M1/M2 via MFMA ----------------
__global__ __launch_bounds__(256) void k_compute_M(const ushort_t* __restrict__ QzB,
        const ushort_t* __restrict__ TB1, const ushort_t* __restrict__ TB2,
        ushort_t* __restrict__ M1Nb, ushort_t* __restrict__ M2Nb) {
    int jt = blockIdx.x, c = blockIdx.y;
    int z = blockIdx.z >> 2, k = blockIdx.z & 3;
    __shared__ __align__(16) ushort_t sQ[4096], sB1[4096], sB2[4096];
    int tid = threadIdx.x;
    stage64a(sQ, QzB + (size_t)(z * LL + jt * 64) * DD, DD, tid);
    size_t tb = (size_t)(k * 8 + c) * 4096;
    stage64a(sB1, TB1 + tb, 64, tid);
    stage64a(sB2, TB2 + tb, 64, tid);
    __syncthreads();
    int w = tid >> 6, lm = tid & 15, lg = (tid & 63) >> 4;
    f32x4 a1[4], a2[4];
#pragma unroll
    for (int nf = 0; nf < 4; ++nf) { a1[nf] = {0.f,0.f,0.f,0.f}; a2[nf] = {0.f,0.f,0.f,0.f}; }
#pragma unroll
    for (int ks = 0; ks < 2; ++ks) {
        int kc = ks * 32 + lg * 8;
        bf16x8 af = frag(sQ, w * 16 + lm, kc);
#pragma unroll
        for (int nf = 0; nf < 4; ++nf) {
            a1[nf] = MFMA(af, frag(sB1, nf * 16 + lm, kc), a1[nf]);
            a2[nf] = MFMA(af, frag(sB2, nf * 16 + lm, kc), a2[nf]);
        }
    }
    size_t base = (((size_t)z * KK + k) * HH + c) * LL;
#pragma unroll
    for (int nf = 0; nf < 4; ++nf)
#pragma unroll
        for (int r = 0; r < 4; ++r) {
            int j = jt * 64 + w * 16 + lg * 4 + r;
            int a = nf * 16 + lm;
            M1Nb[(base + j) * DD + a] = f2b(a1[nf][r]);
            M2Nb[(base + j) * DD + a] = f2b(a2[nf][r]);
        }
}

// ---------------- K3: muxed {collapse 128 blk} {band 2048 blk} {qg 256 blk} ----------------
__global__ __launch_bounds__(256, 4) void k_collaux(const float* __restrict__ Qz,
        const ushort_t* __restrict__ M1Nb, const ushort_t* __restrict__ M2Nb,
        const float* __restrict__ dp, const float* __restrict__ gp, const int* __restrict__ mask,
        ushort_t* __restrict__ MPNb, ushort_t* __restrict__ MMNb,
        ushort_t* __restrict__ MP2Nb, ushort_t* __restrict__ MM2Nb,
        ushort_t* __restrict__ MPT, ushort_t* __restrict__ MMT,
        ushort_t* __restrict__ MP2T, ushort_t* __restrict__ MM2T,
        float* __restrict__ BAND, float* __restrict__ QG) {
    __shared__ __align__(16) ushort_t sT[4 * 64 * 65];
    int tid = threadIdx.x;
    int b = blockIdx.x;
    if (b < 128) {
        int jt = b & 7, zc = b >> 3;
        int z = zc >> 3, c = zc & 7;
        ushort_t* sP1 = sT;
        ushort_t* sM1 = sT + 64 * 65;
        ushort_t* sP2 = sT + 2 * 64 * 65;
        ushort_t* sM2 = sT + 3 * 64 * 65;
        float w4[4], w5[4];
#pragma unroll
        for (int k = 0; k < 4; ++k) { w4[k] = dp[12 + k]; w5[k] = dp[16 + k]; }
        size_t b0 = (((size_t)z * KK * HH + c) * LL + jt * 64) * DD;
        const size_t kstr = (size_t)HH * LL * DD;
        for (int g = tid; g < 512; g += 256) {
            int j = g >> 3, a0 = (g & 7) * 8;
            size_t o = b0 + (size_t)j * DD + a0;
            float p1[8] = {}, q1[8] = {}, p2[8] = {}, q2[8] = {};
#pragma unroll
            for (int k = 0; k < 4; ++k) {
                uint4 v1 = *reinterpret_cast<const uint4*>(&M1Nb[o + k * kstr]);
                uint4 v2 = *reinterpret_cast<const uint4*>(&M2Nb[o + k * kstr]);
                const ushort_t* s1 = reinterpret_cast<const ushort_t*>(&v1);
                const ushort_t* s2 = reinterpret_cast<const ushort_t*>(&v2);
#pragma unroll
                for (int u = 0; u < 8; ++u) {
                    float f1 = b2f(s1[u]), f2v = b2f(s2[u]);
                    p1[u] += w4[k] * f1; q1[u] += w5[k] * f1;
                    p2[u] += w4[k] * f2v; q2[u] += w5[k] * f2v;
                }
            }
            ushort_t t1[8], t2[8], t3[8], t4[8];
#pragma unroll
            for (int u = 0; u < 8; ++u) {
                t1[u] = f2b(p1[u]); t2[u] = f2b(q1[u]); t3[u] = f2b(p2[u]); t4[u] = f2b(q2[u]);
                sP1[(a0 + u) * 65 + j] = t1[u]; sM1[(a0 + u) * 65 + j] = t2[u];
                sP2[(a0 + u) * 65 + j] = t3[u]; sM2[(a0 + u) * 65 + j] = t4[u];
            }
            size_t on = ((size_t)zc * LL + jt * 64 + j) * DD + a0;
            *reinterpret_cast<uint4*>(&MPNb[on])  = *reinterpret_cast<uint4*>(t1);
            *reinterpret_cast<uint4*>(&MMNb[on])  = *reinterpret_cast<uint4*>(t2);
            *reinterpret_cast<uint4*>(&MP2Nb[on]) = *reinterpret_cast<uint4*>(t3);
            *reinterpret_cast<uint4*>(&MM2Nb[on]) = *reinterpret_cast<uint4*>(t4);
        }
        __syncthreads();
        for (int g = tid; g < 512; g += 256) {
            int a = g >> 3, j0 = (g & 7) * 8;
            ushort_t o1[8], o2[8], o3[8], o4[8];
#pragma unroll
            for (int u = 0; u < 8; ++u) {
                o1[u] = sP1[a * 65 + j0 + u]; o2[u] = sM1[a * 65 + j0 + u];
                o3[u] = sP2[a * 65 + j0 + u]; o4[u] = sM2[a * 65 + j0 + u];
            }
            size_t ot = ((size_t)zc * DD + a) * LL + jt * 64 + j0;
            *reinterpret_cast<uint4*>(&MPT[ot])  = *reinterpret_cast<uint4*>(o1);
            *reinterpret_cast<uint4*>(&MMT[ot])  = *reinterpret_cast<uint4*>(o2);
            *reinterpret_cast<uint4*>(&MP2T[ot]) = *reinterpret_cast<uint4*>(o3);
            *reinterpret_cast<uint4*>(&MM2T[ot]) = *reinterpret_cast<uint4*>(o4);
        }
    } else if (b < 2176) {
        int w = (b - 128) * 4 + (tid >> 6);
        int lane = tid & 63;
        int j = w & 511, c = (w >> 9) & 7, z = w >> 12;
        float m[4];
#pragma unroll
        for (int k = 0; k < 4; ++k)
            m[k] = b2f(M1Nb[((((size_t)z * KK + k) * HH + c) * LL + j) * DD + lane]);
        float out = 0.f;
#pragma unroll
        for (int d = -3; d <= 3; ++d) {
            int i = j + d;
            if (i < 0 || i >= LL) continue;
            int idx = d < 0 ? d + 9 : d;
            float t = 0.f;
            if (idx != 0) {
#pragma unroll
                for (int k = 0; k < 4; ++k) t += dp[(idx - 1) * 4 + k] * m[k];
            }
            float s = Qz[(z * LL + i) * DD + lane] * t;
#pragma unroll
            for (int o = 32; o > 0; o >>= 1) s += __shfl_xor(s, o, 64);
            if (lane == d + 3) out = s;
        }
        if (lane < 7) BAND[(size_t)w * 8 + lane] = out;
    } else {
        float* gpS = reinterpret_cast<float*>(sT);
#pragma unroll
        for (int idx = tid; idx < 4096; idx += 256) gpS[(idx >> 6) * 68 + (idx & 63)] = gp[idx];
        __syncthreads();
        int row = (b - 2176) * 4 + (tid >> 6);
        int g = tid & 63;
        float qv = Qz[row * DD + g];
        float s = 0.f;
#pragma unroll 8
        for (int a = 0; a < 64; ++a) s += __shfl(qv, a, 64) * gpS[g * 68 + a];
        if (mask[row] == 0) s = NEGV;
        float m = s;
#pragma unroll
        for (int o = 32; o > 0; o >>= 1) m = fmaxf(m, __shfl_xor(m, o, 64));
        float e = __expf(s - m);
        float sum = e;
#pragma unroll
        for (int o = 32; o > 0; o >>= 1) sum += __shfl_xor(sum, o, 64);
        QG[row * GG + g] = e / sum;
    }
}

// ---------------- K4: fused s_h MFMA + band + mask + row-softmax + dual bf16 write ----------------
__global__ __launch_bounds__(256, 2) void k_shsm32(const ushort_t* __restrict__ QzB,
        const ushort_t* __restrict__ MPNb, const ushort_t* __restrict__ MMNb,
        const float* __restrict__ BAND, const int* __restrict__ mask,
        ushort_t* __restrict__ SHB, ushort_t* __restrict__ SHBT) {
    int ih = blockIdx.x, zc = blockIdx.y;
    int it = ih >> 1, rh = ih & 1;
    int z = zc >> 3;
    int R0 = it * 64 + rh * 32;
    __shared__ __align__(16) ushort_t sA[2048];                 // 32x64
    __shared__ __align__(16) ushort_t sB0[4096], sB1[4096], sBd[4096];
    __shared__ __align__(16) ushort_t tl[2][32 * 72];
    __shared__ float redA[2][32], redB[2][32];
    int tid = threadIdx.x;
    int w = tid >> 6, lm = tid & 15, lg = (tid & 63) >> 4;
    int rw = w & 1, cw = w >> 1;
    // async stage A: 32 rows x 64, 256 granules (one per thread); LDS linear, src pre-swizzled
    {
        int row = tid >> 3, colg = tid & 7;
        gll16(&QzB[(size_t)(z * LL + R0 + row) * DD + ((colg ^ (row & 7)) << 3)],
              sA + (size_t)(w * 64) * 8);
    }
    f32x4 acc[4][4];
#pragma unroll
    for (int jl = 0; jl < 4; ++jl)
#pragma unroll
        for (int nf = 0; nf < 4; ++nf) acc[jl][nf] = {0.f, 0.f, 0.f, 0.f};
    int dstep = it & 3;
#pragma unroll
    for (int s = 0; s < 4; ++s) {
        __syncthreads();
        int jt0 = s, jt1 = 4 + s;
        const ushort_t* src0 = (it >= jt0) ? MPNb : MMNb;
        const ushort_t* src1 = (it >= jt1) ? MPNb : MMNb;
        stage64a(sB0, src0 + ((size_t)zc * LL + jt0 * 64) * DD, DD, tid);
        stage64a(sB1, src1 + ((size_t)zc * LL + jt1 * 64) * DD, DD, tid);
        if (s == dstep)
            stage64a(sBd, MMNb + ((size_t)zc * LL + it * 64) * DD, DD, tid);
        __syncthreads();
        int jtg = cw ? jt1 : jt0;
        const ushort_t* sBx = cw ? sB1 : sB0;
#pragma unroll
        for (int ks = 0; ks < 2; ++ks) {
            int kc = ks * 32 + lg * 8;
            bf16x8 af = frag(sA, rw * 16 + lm, kc);
#pragma unroll
            for (int nf = 0; nf < 4; ++nf)
                acc[s][nf] = MFMA(af, frag(sBx, nf * 16 + lm, kc), acc[s][nf]);
        }
        if (jtg == it) {
            f32x4 accM[4];
#pragma unroll
            for (int nf = 0; nf < 4; ++nf) accM[nf] = {0.f, 0.f, 0.f, 0.f};
#pragma unroll
            for (int ks = 0; ks < 2; ++ks) {
                int kc = ks * 32 + lg * 8;
                bf16x8 af = frag(sA, rw * 16 + lm, kc);
#pragma unroll
                for (int nf = 0; nf < 4; ++nf)
                    accM[nf] = MFMA(af, frag(sBd, nf * 16 + lm, kc), accM[nf]);
            }
#pragma unroll
            for (int nf = 0; nf < 4; ++nf)
#pragma unroll
                for (int r = 0; r < 4; ++r) {
                    int i = R0 + rw * 16 + lg * 4 + r;
                    int j = it * 64 + nf * 16 + lm;
                    if (i <= j) acc[s][nf][r] = accM[nf][r];
                }
        }
    }
    // band overwrite + mask
    int mi[4];
#pragma unroll
    for (int r = 0; r < 4; ++r) mi[r] = mask[z * LL + R0 + rw * 16 + lg * 4 + r];
#pragma unroll
    for (int jl = 0; jl < 4; ++jl) {
        int jtg = cw * 4 + jl;
#pragma unroll
        for (int nf = 0; nf < 4; ++nf) {
            int j = jtg * 64 + nf * 16 + lm;
            int mjv = mask[z * LL + j];
#pragma unroll
            for (int r = 0; r < 4; ++r) {
                int i = R0 + rw * 16 + lg * 4 + r;
                int d = i - j;
                float v = acc[jl][nf][r];
                if (d >= -3 && d <= 3) v = BAND[((size_t)zc * LL + j) * 8 + (d + 3)];
                if (!(mi[r] && mjv)) v = NEGV;
                acc[jl][nf][r] = v;
            }
        }
    }
    // row softmax
    float gm[4], gs[4], inv[4];
#pragma unroll
    for (int r = 0; r < 4; ++r) {
        float m = -1e30f;
#pragma unroll
        for (int jl = 0; jl < 4; ++jl)
#pragma unroll
            for (int nf = 0; nf < 4; ++nf) m = fmaxf(m, acc[jl][nf][r]);
#pragma unroll
        for (int o = 1; o < 16; o <<= 1) m = fmaxf(m, __shfl_xor(m, o, 64));
        gm[r] = m;
    }
    if (lm == 0) {
#pragma unroll
        for (int r = 0; r < 4; ++r) redA[cw][rw * 16 + lg * 4 + r] = gm[r];
    }
    __syncthreads();
#pragma unroll
    for (int r = 0; r < 4; ++r)
        gm[r] = fmaxf(gm[r], redA[cw ^ 1][rw * 16 + lg * 4 + r]);
#pragma unroll
    for (int r = 0; r < 4; ++r) {
        float s = 0.f;
#pragma unroll
        for (int jl = 0; jl < 4; ++jl)
#pragma unroll
            for (int nf = 0; nf < 4; ++nf) {
                float e = __expf(acc[jl][nf][r] - gm[r]);
                acc[jl][nf][r] = e;
                s += e;
            }
#pragma unroll
        for (int o = 1; o < 16; o <<= 1) s += __shfl_xor(s, o, 64);
        gs[r] = s;
    }
    if (lm == 0) {
#pragma unroll
        for (int r = 0; r < 4; ++r) redB[cw][rw * 16 + lg * 4 + r] = gs[r];
    }
    __syncthreads();
#pragma unroll
    for (int r = 0; r < 4; ++r)
        inv[r] = 1.f / (gs[r] + redB[cw ^ 1][rw * 16 + lg * 4 + r]);
    // per-jl: bf16 tiles -> LDS -> coalesced SHB + SHBT writes
#pragma unroll
    for (int jl = 0; jl < 4; ++jl) {
        __syncthreads();
#pragma unroll
        for (int nf = 0; nf < 4; ++nf)
#pragma unroll
            for (int r = 0; r < 4; ++r)
                tl[cw][(rw * 16 + lg * 4 + r) * 72 + nf * 16 + lm] =
                    f2b(acc[jl][nf][r] * inv[r]);
        __syncthreads();
#pragma unroll
        for (int g = tid; g < 512; g += 256) {
            int cwg = g >> 8, rem = g & 255;
            int jtg = cwg * 4 + jl;
            int i_loc = rem >> 3, gj = rem & 7;
            ushort_t tmp[8];
#pragma unroll
            for (int u = 0; u < 8; ++u) tmp[u] = tl[cwg][i_loc * 72 + gj * 8 + u];
            *reinterpret_cast<uint4*>(
                &SHB[((size_t)zc * LL + R0 + i_loc) * LL + jtg * 64 + gj * 8]) =
                *reinterpret_cast<uint4*>(tmp);
        }
#pragma unroll
        for (int g = tid; g < 512; g += 256) {
            int cwg = g >> 8, rem = g & 255;
            int jtg = cwg * 4 + jl;
            int j_loc = rem >> 2, gi = rem & 3;
            ushort_t tmp2[8];
#pragma unroll
            for (int u = 0; u < 8; ++u) tmp2[u] = tl[cwg][(gi * 8 + u) * 72 + j_loc];
            *reinterpret_cast<uint4*>(
                &SHBT[((size_t)zc * LL + jtg * 64 + j_loc) * LL + R0 + gi * 8]) =
                *reinterpret_cast<uint4*>(tmp2);
        }
    }
}

// ---------------- K5: muxed {g12 main GEMMs (512 blk)} {corr12 (1024 blk)} ----------------
__global__ __launch_bounds__(256, 4) void k_g12corr(const ushort_t* __restrict__ SHB,
        const ushort_t* __restrict__ SHBT,
        const ushort_t* __restrict__ MPT, const ushort_t* __restrict__ MMT,
        const ushort_t* __restrict__ MP2T, const ushort_t* __restrict__ MM2T,
        const ushort_t* __restrict__ M1Nb, const ushort_t* __restrict__ M2Nb,
        const ushort_t* __restrict__ MPNb, const ushort_t* __restrict__ MMNb,
        const ushort_t* __restrict__ MP2Nb, const ushort_t* __restrict__ MM2Nb,
        const float* __restrict__ dp, float* __restrict__ PG) {
    __shared__ __align__(16) ushort_t sSH[4096], sM[4096];
    int tid = threadIdx.x;
    int b = blockIdx.x;
    if (b < 512) {
        int it = b & 7, jc = (b >> 3) & 1, zcw = b >> 4;
        int which = zcw >> 4;
        int z = (zcw >> 3) & 1, c = zcw & 7;
        const ushort_t* Amat = which ? SHBT : SHB;
        const ushort_t* TP = which ? MP2T : MPT;
        const ushort_t* TM = which ? MM2T : MMT;
        int w = tid >> 6, lm = tid & 15, lg = (tid & 63) >> 4;
        f32x4 acc[4];
#pragma unroll
        for (int nf = 0; nf < 4; ++nf) acc[nf] = {0.f,0.f,0.f,0.f};
        size_t shbase = ((size_t)(z * HH + c) * LL + it * 64) * LL;
        size_t mbase  = ((size_t)(z * HH + c) * DD) * LL;
        for (int js = 0; js < 4; ++js) {
            int j0 = jc * 256 + js * 64;
            bool dg = (j0 == it * 64);
            bool useP = which == 0 ? (j0 < it * 64) : (j0 > it * 64);
            __syncthreads();
            stage64a(sSH, Amat + shbase + j0, LL, tid);
            stage64a(sM, (dg ? TP : (useP ? TP : TM)) + mbase + j0, LL, tid);
            __syncthreads();
            for (int pass = 0; pass < (dg ? 2 : 1); ++pass) {
                if (pass == 1) {
                    __syncthreads();
                    stage64a(sM, TM + mbase + j0, LL, tid);
                    __syncthreads();
                }
#pragma unroll
                for (int ks = 0; ks < 2; ++ks) {
                    int kc = ks * 32 + lg * 8;
                    int jb = j0 + kc;
                    bf16x8 af = frag(sSH, w * 16 + lm, kc);
                    if (dg) {
                        int i = it * 64 + w * 16 + lm;
                        int cnt = (which == 0) ? iclamp(i - jb, 0, 8) : iclamp(i + 1 - jb, 0, 8);
                        af = maskfrag(af, cnt, (pass == 0) == (which == 0));
                    }
#pragma unroll
                    for (int nf = 0; nf < 4; ++nf)
                        acc[nf] = MFMA(af, frag(sM, nf * 16 + lm, kc), acc[nf]);
                }
            }
        }
        int slot = which * 16 + c * 2 + jc;
#pragma unroll
        for (int nf = 0; nf < 4; ++nf)
#pragma unroll
            for (int r = 0; r < 4; ++r) {
                int i = it * 64 + w * 16 + lg * 4 + r;
                int a = nf * 16 + lm;
                PG[((size_t)(slot * BB + z) * LL + i) * DD + a] = acc[nf][r];
            }
    } else {
        int bid = b - 512;
        int which = bid >> 9; bid &= 511;
        int w = bid * 4 + (tid >> 6);
        int lane = tid & 63;
        int ch = w & 1, i = (w >> 1) & 511, z = w >> 10;
        const ushort_t* Mx = which ? M2Nb : M1Nb;
        const ushort_t* MPb = which ? MP2Nb : MPNb;
        const ushort_t* MMb = which ? MM2Nb : MMNb;
        float acc = 0.f;
        for (int cc = 0; cc < 4; ++cc) {
            int c = ch * 4 + cc;
#pragma unroll
            for (int d = -3; d <= 3; ++d) {
                int j = which ? i + d : i - d;
                if (j < 0 || j >= LL) continue;
                float qh = which ? b2f(SHB[(((size_t)z * HH + c) * LL + j) * LL + i])
                                 : b2f(SHB[(((size_t)z * HH + c) * LL + i) * LL + j]);
                int idx = d < 0 ? d + 9 : d;
                float e = 0.f;
                if (idx != 0) {
#pragma unroll
                    for (int k = 0; k < 4; ++k)
                        e += dp[(idx - 1) * 4 + k] *
                             b2f(Mx[((((size_t)z * KK + k) * HH + c) * LL + j) * DD + lane]);
                }
                const ushort_t* mb = (d > 0) ? MPb : MMb;
                float mn = b2f(mb[(((size_t)z * HH + c) * LL + j) * DD + lane]);
                acc += qh * (e - mn);
            }
        }
        int slot = 32 + which * 2 + ch;
        PG[(((size_t)slot * BB + z) * LL + i) * DD + lane] = acc;
    }
}

// ---------------- K6a: mid-iteration update: q = x + msgs, then softmax -> Qz/QzB ----------------
__global__ __launch_bounds__(256) void k_update_sm(const float* __restrict__ x,
                         const float* __restrict__ PG, const float* __restrict__ QG,
                         const float* __restrict__ gp,
                         float* __restrict__ Qz, ushort_t* __restrict__ QzB) {
    __shared__ __align__(16) float gpS[64][68];
    int tid = threadIdx.x;
#pragma unroll
    for (int idx = tid; idx < 4096; idx += 256) gpS[idx >> 6][idx & 63] = gp[idx];
    __syncthreads();
    int row = blockIdx.x * 4 + (tid >> 6);
    int a = tid & 63;
    float acc = x[row * DD + a];
    float qgv = QG[row * GG + a];
#pragma unroll 8
    for (int g = 0; g < 64; ++g) acc += __shfl(qgv, g, 64) * gpS[g][a];
#pragma unroll 6
    for (int s = 0; s < NSLOT; ++s) acc += PG[((size_t)s * BB * LL + row) * DD + a];
    float m = acc;
#pragma unroll
    for (int o = 32; o > 0; o >>= 1) m = fmaxf(m, __shfl_xor(m, o, 64));
    float e = __expf(acc - m);
    float s2 = e;
#pragma unroll
    for (int o = 32; o > 0; o >>= 1) s2 += __shfl_xor(s2, o, 64);
    float r = e / s2;
    Qz[row * DD + a] = r;
    QzB[row * DD + a] = f2b(r);
}

// ---------------- K6b: final update: out = x + msgs ----------------
__global__ __launch_bounds__(256) void k_update_fin(const float* __restrict__ x,
                         const float* __restrict__ PG, const float* __restrict__ QG,
                         const float* __restrict__ gp, float* __restrict__ outq) {
    __shared__ __align__(16) float gpS[64][68];
    int tid = threadIdx.x;
#pragma unroll
    for (int idx = tid; idx < 4096; idx += 256) gpS[idx >> 6][idx & 63] = gp[idx];
    __syncthreads();
    int row = blockIdx.x * 4 + (tid >> 6);
    int a = tid & 63;
    float acc = x[row * DD + a];
    float qgv = QG[row * GG + a];
#pragma unroll 8
    for (int g = 0; g < 64; ++g) acc += __shfl(qgv, g, 64) * gpS[g][a];
#pragma unroll 6
    for (int s = 0; s < NSLOT; ++s) acc += PG[((size_t)s * BB * LL + row) * DD + a];
    outq[row * DD + a] = acc;
}

extern "C" void kernel_launch(void* const* d_in, const int* in_sizes, int n_in,
                              void* d_out, int out_size, void* d_ws, size_t ws_size,
                              hipStream_t stream) {
    const float* x    = (const float*)d_in[0];
    const int*   mask = (const int*)d_in[1];
    const float* dp   = (const float*)d_in[2];
    const float* T    = (const float*)d_in[3];
    const float* gp   = (const float*)d_in[4];
    float* out = (float*)d_out;

    float* p = (float*)d_ws;
    float* Qz = p;                        p += 65536;
    ushort_t* QzB = (ushort_t*)p;         p += 32768;
    ushort_t* TB1 = (ushort_t*)p;         p += 65536;
    ushort_t* TB2 = (ushort_t*)p;         p += 65536;
    ushort_t* M1Nb = (ushort_t*)p;        p += 1048576;
    ushort_t* M2Nb = (ushort_t*)p;        p += 1048576;
    ushort_t* MPNb  = (ushort_t*)p;       p += 262144;
    ushort_t* MMNb  = (ushort_t*)p;       p += 262144;
    ushort_t* MP2Nb = (ushort_t*)p;       p += 262144;
    ushort_t* MM2Nb = (ushort_t*)p;       p += 262144;
    ushort_t* MPT   = (ushort_t*)p;       p += 262144;
    ushort_t* MMT   = (ushort_t*)p;       p += 262144;
    ushort_t* MP2T  = (ushort_t*)p;       p += 262144;
    ushort_t* MM2T  = (ushort_t*)p;       p += 262144;
    float* BAND = p;                      p += 65536;
    ushort_t* SHB  = (ushort_t*)p;        p += 2097152;
    ushort_t* SHBT = (ushort_t*)p;        p += 2097152;
    float* QG   = p;                      p += 65536;
    float* PG   = p;                      p += (size_t)NSLOT * 65536;

    hipLaunchKernelGGL(k_prepT, dim3(32), dim3(256), 0, stream, T, TB1, TB2);
    hipLaunchKernelGGL(k_softmax_qz, dim3(256), dim3(256), 0, stream, x, Qz, QzB);

    for (int iter = 0; iter < 2; ++iter) {
        hipLaunchKernelGGL(k_compute_M, dim3(8, 8, 8), dim3(256), 0, stream, QzB, TB1, TB2, M1Nb, M2Nb);
        hipLaunchKernelGGL(k_collaux, dim3(2432), dim3(256), 0, stream, Qz, M1Nb, M2Nb, dp, gp, mask,
                           MPNb, MMNb, MP2Nb, MM2Nb, MPT, MMT, MP2T, MM2T, BAND, QG);
        hipLaunchKernelGGL(k_shsm32, dim3(16, 16), dim3(256), 0, stream, QzB, MPNb, MMNb, BAND, mask,
                           SHB, SHBT);
        hipLaunchKernelGGL(k_g12corr, dim3(1536), dim3(256), 0, stream, SHB, SHBT,
                           MPT, MMT, MP2T, MM2T, M1Nb, M2Nb,
                           MPNb, MMNb, MP2Nb, MM2Nb, dp, PG);
        if (iter == 0)
            hipLaunchKernelGGL(k_update_sm, dim3(256), dim3(256), 0, stream, x, PG, QG, gp, Qz, QzB);
        else
            hipLaunchKernelGGL(k_update_fin, dim3(256), dim3(256), 0, stream, x, PG, QG, gp, out);
    }
}